// Round 10
// baseline (361.389 us; speedup 1.0000x reference)
//
#include <hip/hip_runtime.h>
#include <stdint.h>

#define TT 512
#define BB 4096
#define NT4 1024   // tiles of 4 batch columns
#define LOG2E 1.4426950408889634f

typedef _Float16 half8_t __attribute__((ext_vector_type(8)));
typedef __fp16 fp16x2_t __attribute__((ext_vector_type(2)));
typedef float f32x4 __attribute__((ext_vector_type(4)));

union FragU { uint4 u4; half8_t h8; };
union PkU { fp16x2_t h2; unsigned int u; };

__device__ __forceinline__ float rcp_(float x){ return __builtin_amdgcn_rcpf(x); }
__device__ __forceinline__ float exp2_(float x){ return __builtin_amdgcn_exp2f(x); }
__device__ __forceinline__ float elu_(float x){ return x > 0.0f ? x : (exp2_(x * LOG2E) - 1.0f); }
__device__ __forceinline__ int mini_(int a, int b){ return a < b ? a : b; }
__device__ __forceinline__ float maskhi_(float x){ return __uint_as_float(__float_as_uint(x) & 0xFFFFE000u); }
__device__ __forceinline__ unsigned int pkrtz_(float a, float b){
    PkU p; p.h2 = __builtin_amdgcn_cvt_pkrtz(a, b); return p.u;
}

__device__ __forceinline__ f32x4 MFMA(half8_t a, half8_t b, f32x4 c) {
    return __builtin_amdgcn_mfma_f32_16x16x32_f16(a, b, c, 0, 0, 0);
}

__device__ __forceinline__ f32x4 ld4_(const float* p){ return *(const f32x4*)p; }

// pack 8 f32 -> 8 f16 with scale (A-fragment slice; row = lane&15, k = 8*(lane>>4)+e)
__device__ __forceinline__ half8_t packA8s(const float* s, float sc) {
    half8_t h;
#pragma unroll
    for (int k = 0; k < 8; ++k) h[k] = (_Float16)(s[k] * sc);
    return h;
}

// select reg j (runtime 0..3) from f32x4 via 3 cndmask (static indices only)
__device__ __forceinline__ float sel4_(f32x4 a, int j) {
    float lo = (j & 1) ? a[1] : a[0];
    float hi = (j & 1) ? a[3] : a[2];
    return (j & 2) ? hi : lo;
}

// One-unit LSTM cell. Inputs PRESCALED: i,f,o by log2e; g by 2*log2e.
// Shared-rcp: R = rcp((1+ei)(1+ef)(1+eg)(1+eo)); 1/(1+ek) = R*prod_{j!=k}.
// 7 transcendentals (5 exp2 + 2 rcp). |g'|<~24 -> P<2^96, no overflow.
__device__ __forceinline__ float cell1_(float gi, float gf, float gg, float go, float& c) {
    float ei = exp2_(-gi), ef = exp2_(-gf), eg = exp2_(-gg), eo = exp2_(-go);
    float ai = 1.0f + ei, af = 1.0f + ef, ag = 1.0f + eg, ao = 1.0f + eo;
    float p2 = ai * af, p3 = p2 * ag, P = p3 * ao;
    float R  = rcp_(P);
    float sgo = ag * ao;
    float I = R * (af * sgo);
    float F = R * (ai * sgo);
    float G = fmaf(2.0f, R * (p2 * ao), -1.0f);
    float O = R * p3;
    c = fmaf(F, c, I * G);
    float et = exp2_(c * (-2.0f * LOG2E));
    float T  = fmaf(2.0f, rcp_(1.0f + et), -1.0f);
    return O * T;
}

// Dup-4 scheme: 4 real cols/chain; B col-slot b carries col c=b&3, so all 4
// C-regs of lane (q,b) are valid for col c; lane uses reg j=b>>2 -> unit
// u=4q+j (1 unit/lane). 2048 chains -> 512 WGs x 256thr = 2 WG/CU =
// 2 waves/SIMD: the second wave's issue hides the first's LDS/MFMA/exp stall.
//
// phase A LDS col region (80B stride): [0,32) h_hi fp16 units 0-15 (written
// b16 per lane at u*2); [32,48) x slot: [x_hi,x_lo,0...] (b32 written by the
// q==2,j==0 lane each step); [48,64) zeros. B-frag read b128 at c*80+q*16:
// q=0: hi u0-7, q=1: hi u8-15, q=2: x slot, q=3: zeros.
// Matching A-frag (K=32): cols 0-15 = Whh*SC, col 16 = col 17 = Wih*SC,
// cols 18-31 = 0. Bias rides the MFMA C-input (f32, exact).
//
// phase B LDS col region: [0,32) h1_hi, [32,64) h1_lo (fp28 recurrence kept).
// read b128 at c*80 + (q&1)*16 + (q>>1)*32; A = [Whh | Whh] over K=32.

// ---------------- phase A: layer 0 (input dim 1), both directions ----------------
struct PA {
    const float *x;
    const float *WihF, *WhhF, *bihF, *bhhF;
    const float *WihB, *WhhB, *bihB, *bhhB;
    char* ws;   // [tile4][t][256B]: col c at c*64: [f u0-15 hi | b u0-15 hi] fp16
};

__global__ __launch_bounds__(256) void phaseA_k(PA p) {
    __shared__ uint4 lds4[4 * 20];   // 4 waves x 320 B
    const int tid = threadIdx.x;
    const int lane = tid & 63;
    const int wv   = tid >> 6;
    char* lds = (char*)lds4 + wv * 320;
    const int q = lane >> 4, b = lane & 15, c = b & 3, j = b >> 2;
    const int chain = blockIdx.x * 4 + wv;       // 2048 chains = 1024 tiles x 2 dirs
    const int tile = chain >> 1, dir = chain & 1;

    const float* Wih = dir ? p.WihB : p.WihF;
    const float* Whh = dir ? p.WhhB : p.WhhF;
    const float* bih = dir ? p.bihB : p.bihF;
    const float* bhh = dir ? p.bhhB : p.bhhF;

    // A-frags: K=32 = [h_hi(16) | x_hi,x_lo | zeros]
    auto mkA = [&](int m, float sc)->half8_t {
        if (q < 2) return packA8s(Whh + (16*m + b)*16 + 8*q, sc);
        half8_t h = {(_Float16)0, (_Float16)0, (_Float16)0, (_Float16)0,
                     (_Float16)0, (_Float16)0, (_Float16)0, (_Float16)0};
        if (q == 2) {
            float wv_ = Wih[16*m + b] * sc;   // Wih0 is [64 x 1]
            h[0] = (_Float16)wv_;
            h[1] = (_Float16)wv_;
        }
        return h;
    };
    half8_t w0 = mkA(0, LOG2E);
    half8_t w1 = mkA(1, LOG2E);
    half8_t w2 = mkA(2, 2.0f*LOG2E);
    half8_t w3 = mkA(3, LOG2E);

    f32x4 bias0 = (ld4_(bih +      4*q) + ld4_(bhh +      4*q)) * LOG2E;
    f32x4 bias1 = (ld4_(bih + 16 + 4*q) + ld4_(bhh + 16 + 4*q)) * LOG2E;
    f32x4 bias2 = (ld4_(bih + 32 + 4*q) + ld4_(bhh + 32 + 4*q)) * (2.0f*LOG2E);
    f32x4 bias3 = (ld4_(bih + 48 + 4*q) + ld4_(bhh + 48 + 4*q)) * LOG2E;

    const int u   = 4*q + j;
    const int rdo = c*80 + q*16;       // frag read offset
    const int who = c*80 + u*2;        // h_hi b16 write
    const int xwo = c*80 + 32;         // x slot b32 write
    const bool xw = (q == 2) && (j == 0);

    { unsigned int* z = (unsigned int*)lds;      // zero whole 320B region
      for (int k = lane; k < 80; k += 64) z[k] = 0u; }
    __builtin_amdgcn_wave_barrier();

    float cC = 0.f;

    const char* xbase = (const char*)p.x + (size_t)tile*4*TT*4;   // uniform
    const int   xoff  = c*TT*4;                                   // invariant voffset
    char*       wsbase = p.ws + (size_t)tile*TT*256;              // uniform
    const int   woff  = c*64 + dir*32 + u*2;

    auto xld = [&](int s_)->float {
        int s = mini_(s_, TT-1);
        int t = dir ? (TT-1-s) : s;
        return *(const float*)(xbase + (size_t)t*4 + xoff);
    };

    auto step = [&](float xv, int t) {
        float mh = maskhi_(xv);
        unsigned int xp = pkrtz_(mh, xv - mh);   // [x_hi, x_lo]
        if (xw) *(unsigned int*)(lds + xwo) = xp;
        __builtin_amdgcn_wave_barrier();
        FragU hf; hf.u4 = *(const uint4*)(lds + rdo);
        f32x4 a0 = MFMA(w0, hf.h8, bias0);
        f32x4 a1 = MFMA(w1, hf.h8, bias1);
        f32x4 a2 = MFMA(w2, hf.h8, bias2);
        f32x4 a3 = MFMA(w3, hf.h8, bias3);
        float h = cell1_(sel4_(a0, j), sel4_(a1, j), sel4_(a2, j), sel4_(a3, j), cC);
        __fp16 h16 = (__fp16)h;
        *(__fp16*)(lds + who) = h16;
        *(__fp16*)(wsbase + (size_t)t*256 + woff) = h16;
        __builtin_amdgcn_wave_barrier();
    };

    float xv0 = xld(0), xv1 = xld(1), xv2 = xld(2), xv3 = xld(3);
    for (int s = 0; s < TT; s += 4) {
        const int t0 = dir ? (TT-1-s) : s;
        const int d  = dir ? -1 : 1;
        step(xv0, t0      ); xv0 = xld(s+4);
        step(xv1, t0 + d  ); xv1 = xld(s+5);
        step(xv2, t0 + 2*d); xv2 = xld(s+6);
        step(xv3, t0 + 3*d); xv3 = xld(s+7);
    }
}

// ---------------- phase B: layer 1 (input dim 32 from ws), both directions ----------------
struct PB {
    const float *WihF, *WhhF, *bihF, *bhhF;
    const float *WihB, *WhhB, *bihB, *bhhB;
    const char* ws;
    float* hT;   // [dir][batch][16] f32
};

__global__ __launch_bounds__(256) void phaseB_k(PB p) {
    __shared__ uint4 lds4[4 * 20];
    const int tid = threadIdx.x;
    const int lane = tid & 63;
    const int wv   = tid >> 6;
    char* lds = (char*)lds4 + wv * 320;
    const int q = lane >> 4, b = lane & 15, c = b & 3, j = b >> 2;
    const int chain = blockIdx.x * 4 + wv;
    const int tile = chain >> 1, dir = chain & 1;

    const float* Wih = dir ? p.WihB : p.WihF;
    const float* Whh = dir ? p.WhhB : p.WhhF;
    const float* bih = dir ? p.bihB : p.bihF;
    const float* bhh = dir ? p.bhhB : p.bhhF;

    const float SC0 = LOG2E, SC1 = LOG2E, SC2 = 2.0f*LOG2E, SC3 = LOG2E;

    half8_t wi0 = packA8s(Wih + (     b)*32 + 8*q, SC0);  // K=32 = [h0f;h0b]
    half8_t wi1 = packA8s(Wih + (16 + b)*32 + 8*q, SC1);
    half8_t wi2 = packA8s(Wih + (32 + b)*32 + 8*q, SC2);
    half8_t wi3 = packA8s(Wih + (48 + b)*32 + 8*q, SC3);

    half8_t wh0 = packA8s(Whh + (     b)*16 + 8*(q&1), SC0);  // [Whh | Whh] hi;lo
    half8_t wh1 = packA8s(Whh + (16 + b)*16 + 8*(q&1), SC1);
    half8_t wh2 = packA8s(Whh + (32 + b)*16 + 8*(q&1), SC2);
    half8_t wh3 = packA8s(Whh + (48 + b)*16 + 8*(q&1), SC3);

    f32x4 bias0 = (ld4_(bih +      4*q) + ld4_(bhh +      4*q)) * SC0;
    f32x4 bias1 = (ld4_(bih + 16 + 4*q) + ld4_(bhh + 16 + 4*q)) * SC1;
    f32x4 bias2 = (ld4_(bih + 32 + 4*q) + ld4_(bhh + 32 + 4*q)) * SC2;
    f32x4 bias3 = (ld4_(bih + 48 + 4*q) + ld4_(bhh + 48 + 4*q)) * SC3;

    const int u   = 4*q + j;
    const int rdo = c*80 + (q&1)*16 + (q>>1)*32;   // [hi u0-7|hi u8-15|lo u0-7|lo u8-15]
    const int who = c*80 + u*2;                    // hi b16 (lo at +32)

    { unsigned int* z = (unsigned int*)lds;
      for (int k = lane; k < 80; k += 64) z[k] = 0u; }
    __builtin_amdgcn_wave_barrier();

    float cC = 0.f, hC = 0.f;

    const char* wsbase = p.ws + (size_t)tile*TT*256;   // uniform
    const int   xoff   = c*64 + q*16;                  // invariant voffset

    auto xld = [&](int s_)->uint4 {
        int s = mini_(s_, TT-1);
        int t = dir ? (TT-1-s) : s;
        return *(const uint4*)(wsbase + (size_t)t*256 + xoff);
    };

    auto step = [&](uint4 xin) {
        FragU xf; xf.u4 = xin;
        FragU hf; hf.u4 = *(const uint4*)(lds + rdo);
        f32x4 a0 = MFMA(wi0, xf.h8, bias0);
        f32x4 a1 = MFMA(wi1, xf.h8, bias1);
        f32x4 a2 = MFMA(wi2, xf.h8, bias2);
        f32x4 a3 = MFMA(wi3, xf.h8, bias3);
        a0 = MFMA(wh0, hf.h8, a0);
        a1 = MFMA(wh1, hf.h8, a1);
        a2 = MFMA(wh2, hf.h8, a2);
        a3 = MFMA(wh3, hf.h8, a3);
        hC = cell1_(sel4_(a0, j), sel4_(a1, j), sel4_(a2, j), sel4_(a3, j), cC);
        float mh = maskhi_(hC);
        *(__fp16*)(lds + who) = (__fp16)mh;
        *(__fp16*)(lds + who + 32) = (__fp16)(hC - mh);
        __builtin_amdgcn_wave_barrier();
    };

    uint4 xb0 = xld(0), xb1 = xld(1), xb2 = xld(2), xb3 = xld(3);
    for (int s = 0; s < TT; s += 4) {
        step(xb0); xb0 = xld(s+4);
        step(xb1); xb1 = xld(s+5);
        step(xb2); xb2 = xld(s+6);
        step(xb3); xb3 = xld(s+7);
    }

    const int batch = tile*4 + c;
    p.hT[((size_t)(dir ? BB : 0) + batch)*16 + u] = hC;
}

// ---------------- phase C: MLP head ----------------
struct PC {
    const float* hT;
    const float *W1, *b1, *W2, *b2;
    float* out;
};

__global__ __launch_bounds__(64) void head_k(PC p) {
    const int B = blockIdx.x * 64 + threadIdx.x;
    const float* hf = p.hT + (size_t)B*16;
    const float* hb = p.hT + ((size_t)BB + B)*16;

    float z0[32];
#pragma unroll
    for (int k = 0; k < 16; ++k) z0[k] = elu_(hb[k]);       // feat = [hT_b, hT_f]
#pragma unroll
    for (int k = 0; k < 16; ++k) z0[16+k] = elu_(hf[k]);

    float z1[25];
#pragma unroll
    for (int o = 0; o < 25; ++o) {
        float a = p.b1[o];
#pragma unroll
        for (int k = 0; k < 32; ++k) a = fmaf(p.W1[o*32 + k], z0[k], a);
        z1[o] = elu_(a);
    }
#pragma unroll
    for (int o = 0; o < 20; ++o) {
        float a = p.b2[o];
#pragma unroll
        for (int k = 0; k < 25; ++k) a = fmaf(p.W2[o*25 + k], z1[k], a);
        p.out[(size_t)B*20 + o] = elu_(a);
    }
}

extern "C" void kernel_launch(void* const* d_in, const int* in_sizes, int n_in,
                              void* d_out, int out_size, void* d_ws, size_t ws_size,
                              hipStream_t stream) {
    (void)in_sizes; (void)n_in; (void)out_size;

    const size_t frag_bytes = (size_t)NT4 * TT * 256;                 // 128 MiB
    const size_t hT_bytes   = (size_t)2 * BB * 16 * sizeof(float);    // 512 KiB
    size_t hT_off = (ws_size >= frag_bytes + hT_bytes) ? frag_bytes
                                                       : (ws_size - hT_bytes);
    char* ws = (char*)d_ws;
    float* hT = (float*)(ws + hT_off);

    PA pa;
    pa.x = (const float*)d_in[0];
    pa.WihF = (const float*)d_in[1];  pa.WhhF = (const float*)d_in[2];
    pa.bihF = (const float*)d_in[3];  pa.bhhF = (const float*)d_in[4];
    pa.WihB = (const float*)d_in[5];  pa.WhhB = (const float*)d_in[6];
    pa.bihB = (const float*)d_in[7];  pa.bhhB = (const float*)d_in[8];
    pa.ws = ws;
    hipLaunchKernelGGL(phaseA_k, dim3(512), dim3(256), 0, stream, pa);

    PB pb;
    pb.WihF = (const float*)d_in[9];   pb.WhhF = (const float*)d_in[10];
    pb.bihF = (const float*)d_in[11];  pb.bhhF = (const float*)d_in[12];
    pb.WihB = (const float*)d_in[13];  pb.WhhB = (const float*)d_in[14];
    pb.bihB = (const float*)d_in[15];  pb.bhhB = (const float*)d_in[16];
    pb.ws = ws; pb.hT = hT;
    hipLaunchKernelGGL(phaseB_k, dim3(512), dim3(256), 0, stream, pb);

    PC pc;
    pc.hT = hT;
    pc.W1 = (const float*)d_in[17]; pc.b1 = (const float*)d_in[18];
    pc.W2 = (const float*)d_in[19]; pc.b2 = (const float*)d_in[20];
    pc.out = (float*)d_out;
    hipLaunchKernelGGL(head_k, dim3(BB/64), dim3(64), 0, stream, pc);
}

// Round 11
// 306.305 us; speedup vs baseline: 1.1798x; 1.1798x over previous
//
#include <hip/hip_runtime.h>
#include <stdint.h>

#define TT 512
#define BB 4096
#define NT8 512   // tiles of 8 batch columns
#define LOG2E 1.4426950408889634f

typedef _Float16 half8_t __attribute__((ext_vector_type(8)));
typedef __fp16 fp16x2_t __attribute__((ext_vector_type(2)));
typedef float f32x4 __attribute__((ext_vector_type(4)));
typedef float f32x2 __attribute__((ext_vector_type(2)));

union FragU { uint4 u4; half8_t h8; };
union PkU { fp16x2_t h2; unsigned int u; };

__device__ __forceinline__ float rcp_(float x){ return __builtin_amdgcn_rcpf(x); }
__device__ __forceinline__ float exp2_(float x){ return __builtin_amdgcn_exp2f(x); }
__device__ __forceinline__ float elu_(float x){ return x > 0.0f ? x : (exp2_(x * LOG2E) - 1.0f); }
__device__ __forceinline__ int mini_(int a, int b){ return a < b ? a : b; }
__device__ __forceinline__ float maskhi_(float x){ return __uint_as_float(__float_as_uint(x) & 0xFFFFE000u); }
__device__ __forceinline__ unsigned int pkrtz_(float a, float b){
    PkU p; p.h2 = __builtin_amdgcn_cvt_pkrtz(a, b); return p.u;
}
__device__ __forceinline__ unsigned int pkrne_(float a, float b){
    PkU p; p.h2[0] = (__fp16)a; p.h2[1] = (__fp16)b; return p.u;
}

__device__ __forceinline__ f32x4 MFMA(half8_t a, half8_t b, f32x4 c) {
    return __builtin_amdgcn_mfma_f32_16x16x32_f16(a, b, c, 0, 0, 0);
}

__device__ __forceinline__ f32x4 ld4_(const float* p){ return *(const f32x4*)p; }

// pack 8 f32 -> 8 f16 with scale (A-fragment slice; row = lane&15, k = 8*(lane>>4)+e)
__device__ __forceinline__ half8_t packA8s(const float* s, float sc) {
    half8_t h;
#pragma unroll
    for (int k = 0; k < 8; ++k) h[k] = (_Float16)(s[k] * sc);
    return h;
}
__device__ __forceinline__ half8_t zero8_() {
    half8_t h;
#pragma unroll
    for (int k = 0; k < 8; ++k) h[k] = (_Float16)0.0f;
    return h;
}

// Two-unit LSTM cell, f32x2-packed, shared-rcp sigmoids.
// Inputs PRESCALED: i,f,o rows by log2e; g rows by 2*log2e.
// 7 trans/unit (5 exp2 + 2 rcp). |g'|<~24 -> P<2^96, no overflow.
__device__ __forceinline__ void cell2p_(f32x2 gi, f32x2 gf, f32x2 gg, f32x2 go,
                                        f32x2& c, f32x2& h) {
    f32x2 ei, ef, eg, eo;
    ei[0] = exp2_(-gi[0]); ei[1] = exp2_(-gi[1]);
    ef[0] = exp2_(-gf[0]); ef[1] = exp2_(-gf[1]);
    eg[0] = exp2_(-gg[0]); eg[1] = exp2_(-gg[1]);
    eo[0] = exp2_(-go[0]); eo[1] = exp2_(-go[1]);
    const f32x2 one = {1.0f, 1.0f};
    f32x2 ai = one + ei, af = one + ef, ag = one + eg, ao = one + eo;
    f32x2 pif = ai * af, pgo = ag * ao;
    f32x2 P = pif * pgo;
    f32x2 R; R[0] = rcp_(P[0]); R[1] = rcp_(P[1]);
    f32x2 I = R * (af * pgo);
    f32x2 F = R * (ai * pgo);
    f32x2 Gt = R * (pif * ao);
    f32x2 O = R * (pif * ag);
    f32x2 G = Gt + Gt - one;            // tanh(g) = 2*sigmoid(2g)-1
    c = F * c + I * G;
    f32x2 ct = c * (-2.0f * LOG2E);
    f32x2 et; et[0] = exp2_(ct[0]); et[1] = exp2_(ct[1]);
    f32x2 den = one + et;
    f32x2 Rt; Rt[0] = rcp_(den[0]); Rt[1] = rcp_(den[1]);
    f32x2 T = Rt + Rt - one;
    h = O * T;
}

// Dup-8 scheme (8 real cols/chain, B col-slots 8-15 ≡ 0-7): lane (q,b),
// c=b&7, hi8=(b>=8) owns units uu=4q+2*hi8, uu+1 of col c, packed as one
// u32 hh (2x fp16 RNE). Recurrence is fp16-only (hi): K=0-15 = h_hi,
// K=16-31 = 0 (phaseB) or [x_hi,x_lo,0..] (phaseA).
//
// h-exchange is 4 ds_bpermute (__shfl), NO LDS, NO barriers:
// dest lane (q<2, b) frag word w (= units 8q+2w, 8q+2w+1) pulls hh from
// owner lane 32q + 16*(w>>1) + 8*(w&1) + c. Lanes q>=2: words = 0
// (except phaseA q=2 word0 = [x_hi,x_lo]).

// ---------------- phase A: layer 0 (input dim 1), both directions ----------------
struct PA {
    const float *x;
    const float *WihF, *WhhF, *bihF, *bhhF;
    const float *WihB, *WhhB, *bihB, *bhhB;
    char* ws;   // [tile8][t][512B]: col c at c*64: [f u0-15 hi | b u0-15 hi] fp16
};

__global__ __launch_bounds__(256) void phaseA_k(PA p) {
    const int tid = threadIdx.x;
    const int lane = tid & 63;
    const int wv   = tid >> 6;
    const int q = lane >> 4, b = lane & 15, c = b & 7;
    const bool hi8 = b >= 8;
    const int chain = blockIdx.x * 4 + wv;       // 1024 chains = 512 tiles x 2 dirs
    const int tile = chain >> 1, dir = chain & 1;

    const float* Wih = dir ? p.WihB : p.WihF;
    const float* Whh = dir ? p.WhhB : p.WhhF;
    const float* bih = dir ? p.bihB : p.bihF;
    const float* bhh = dir ? p.bhhB : p.bhhF;

    // A-frags: K=32 = [Whh(16) | Wih,Wih | zeros(14)]
    auto mkA = [&](int m, float sc)->half8_t {
        if (q < 2) return packA8s(Whh + (16*m + b)*16 + 8*q, sc);
        half8_t h = zero8_();
        if (q == 2) {
            float w = Wih[16*m + b] * sc;   // Wih0 is [64 x 1]
            h[0] = (_Float16)w;
            h[1] = (_Float16)w;
        }
        return h;
    };
    half8_t A0 = mkA(0, LOG2E);
    half8_t A1 = mkA(1, LOG2E);
    half8_t A2 = mkA(2, 2.0f*LOG2E);
    half8_t A3 = mkA(3, LOG2E);

    f32x4 bias0 = (ld4_(bih +      4*q) + ld4_(bhh +      4*q)) * LOG2E;
    f32x4 bias1 = (ld4_(bih + 16 + 4*q) + ld4_(bhh + 16 + 4*q)) * LOG2E;
    f32x4 bias2 = (ld4_(bih + 32 + 4*q) + ld4_(bhh + 32 + 4*q)) * (2.0f*LOG2E);
    f32x4 bias3 = (ld4_(bih + 48 + 4*q) + ld4_(bhh + 48 + 4*q)) * LOG2E;

    const int uu = 4*q + (hi8 ? 2 : 0);
    // shfl source lanes for frag words 0..3 (valid for dest q<2; others discard)
    const int sa0 = 32*(q&1) + c;
    const int sa1 = sa0 + 8;
    const int sa2 = sa0 + 16;
    const int sa3 = sa0 + 24;
    const bool qlt2 = q < 2;
    const bool q2   = q == 2;

    unsigned int hh = 0u;           // this lane's packed unit pair (fp16 RNE)
    f32x2 cc = {0.f, 0.f};

    const char* xbase = (const char*)p.x + (size_t)tile*8*TT*4;   // uniform
    const int   xoff  = c*TT*4;                                   // invariant voffset
    char*       wsbase = p.ws + (size_t)tile*TT*512;              // uniform
    const int   woff  = c*64 + dir*32 + uu*2;

    auto xld = [&](int s_)->float {
        int s = mini_(s_, TT-1);
        int t = dir ? (TT-1-s) : s;
        return *(const float*)(xbase + (size_t)t*4 + xoff);
    };

    auto step = [&](float xv, int t) {
        float mh = maskhi_(xv);
        unsigned int xp = pkrtz_(mh, xv - mh);   // [x_hi, x_lo]
        unsigned int s0 = (unsigned int)__shfl((int)hh, sa0);
        unsigned int s1 = (unsigned int)__shfl((int)hh, sa1);
        unsigned int s2 = (unsigned int)__shfl((int)hh, sa2);
        unsigned int s3 = (unsigned int)__shfl((int)hh, sa3);
        FragU hf;
        hf.u4.x = qlt2 ? s0 : (q2 ? xp : 0u);
        hf.u4.y = qlt2 ? s1 : 0u;
        hf.u4.z = qlt2 ? s2 : 0u;
        hf.u4.w = qlt2 ? s3 : 0u;
        f32x4 r0 = MFMA(A0, hf.h8, bias0);
        f32x4 r1 = MFMA(A1, hf.h8, bias1);
        f32x4 r2 = MFMA(A2, hf.h8, bias2);
        f32x4 r3 = MFMA(A3, hf.h8, bias3);
        f32x2 gi, gf, gg, go;
        gi[0] = hi8 ? r0[2] : r0[0]; gi[1] = hi8 ? r0[3] : r0[1];
        gf[0] = hi8 ? r1[2] : r1[0]; gf[1] = hi8 ? r1[3] : r1[1];
        gg[0] = hi8 ? r2[2] : r2[0]; gg[1] = hi8 ? r2[3] : r2[1];
        go[0] = hi8 ? r3[2] : r3[0]; go[1] = hi8 ? r3[3] : r3[1];
        f32x2 hv;
        cell2p_(gi, gf, gg, go, cc, hv);
        hh = pkrne_(hv[0], hv[1]);
        *(unsigned int*)(wsbase + (size_t)t*512 + woff) = hh;
    };

    float xv0 = xld(0), xv1 = xld(1), xv2 = xld(2), xv3 = xld(3);
    for (int s = 0; s < TT; s += 4) {
        const int t0 = dir ? (TT-1-s) : s;
        const int d  = dir ? -1 : 1;
        step(xv0, t0      ); xv0 = xld(s+4);
        step(xv1, t0 + d  ); xv1 = xld(s+5);
        step(xv2, t0 + 2*d); xv2 = xld(s+6);
        step(xv3, t0 + 3*d); xv3 = xld(s+7);
    }
}

// ---------------- phase B: layer 1 (input dim 32 from ws), both directions ----------------
struct PB {
    const float *WihF, *WhhF, *bihF, *bhhF;
    const float *WihB, *WhhB, *bihB, *bhhB;
    const char* ws;
    float* hT;   // [dir][batch][16] f32
};

__global__ __launch_bounds__(256) void phaseB_k(PB p) {
    const int tid = threadIdx.x;
    const int lane = tid & 63;
    const int wv   = tid >> 6;
    const int q = lane >> 4, b = lane & 15, c = b & 7;
    const bool hi8 = b >= 8;
    const int chain = blockIdx.x * 4 + wv;
    const int tile = chain >> 1, dir = chain & 1;

    const float* Wih = dir ? p.WihB : p.WihF;
    const float* Whh = dir ? p.WhhB : p.WhhF;
    const float* bih = dir ? p.bihB : p.bihF;
    const float* bhh = dir ? p.bhhB : p.bhhF;

    const float SC0 = LOG2E, SC1 = LOG2E, SC2 = 2.0f*LOG2E, SC3 = LOG2E;

    half8_t wi0 = packA8s(Wih + (     b)*32 + 8*q, SC0);  // K=32 = [h0f;h0b]
    half8_t wi1 = packA8s(Wih + (16 + b)*32 + 8*q, SC1);
    half8_t wi2 = packA8s(Wih + (32 + b)*32 + 8*q, SC2);
    half8_t wi3 = packA8s(Wih + (48 + b)*32 + 8*q, SC3);

    // wh: K=32 = [Whh(16) | zeros] (fp16-only recurrence)
    half8_t wh0 = (q < 2) ? packA8s(Whh + (     b)*16 + 8*q, SC0) : zero8_();
    half8_t wh1 = (q < 2) ? packA8s(Whh + (16 + b)*16 + 8*q, SC1) : zero8_();
    half8_t wh2 = (q < 2) ? packA8s(Whh + (32 + b)*16 + 8*q, SC2) : zero8_();
    half8_t wh3 = (q < 2) ? packA8s(Whh + (48 + b)*16 + 8*q, SC3) : zero8_();

    f32x4 bias0 = (ld4_(bih +      4*q) + ld4_(bhh +      4*q)) * SC0;
    f32x4 bias1 = (ld4_(bih + 16 + 4*q) + ld4_(bhh + 16 + 4*q)) * SC1;
    f32x4 bias2 = (ld4_(bih + 32 + 4*q) + ld4_(bhh + 32 + 4*q)) * SC2;
    f32x4 bias3 = (ld4_(bih + 48 + 4*q) + ld4_(bhh + 48 + 4*q)) * SC3;

    const int uu = 4*q + (hi8 ? 2 : 0);
    const int sa0 = 32*(q&1) + c;
    const int sa1 = sa0 + 8;
    const int sa2 = sa0 + 16;
    const int sa3 = sa0 + 24;
    const bool qlt2 = q < 2;

    unsigned int hh = 0u;
    f32x2 cc = {0.f, 0.f};
    f32x2 hv = {0.f, 0.f};

    const char* wsbase = p.ws + (size_t)tile*TT*512;   // uniform
    const int   xoff   = c*64 + q*16;                  // invariant voffset

    auto xld = [&](int s_)->uint4 {
        int s = mini_(s_, TT-1);
        int t = dir ? (TT-1-s) : s;
        return *(const uint4*)(wsbase + (size_t)t*512 + xoff);
    };

    auto step = [&](uint4 xin) {
        FragU xf; xf.u4 = xin;
        unsigned int s0 = (unsigned int)__shfl((int)hh, sa0);
        unsigned int s1 = (unsigned int)__shfl((int)hh, sa1);
        unsigned int s2 = (unsigned int)__shfl((int)hh, sa2);
        unsigned int s3 = (unsigned int)__shfl((int)hh, sa3);
        FragU hf;
        hf.u4.x = qlt2 ? s0 : 0u;
        hf.u4.y = qlt2 ? s1 : 0u;
        hf.u4.z = qlt2 ? s2 : 0u;
        hf.u4.w = qlt2 ? s3 : 0u;
        f32x4 r0 = MFMA(wi0, xf.h8, bias0);
        f32x4 r1 = MFMA(wi1, xf.h8, bias1);
        f32x4 r2 = MFMA(wi2, xf.h8, bias2);
        f32x4 r3 = MFMA(wi3, xf.h8, bias3);
        r0 = MFMA(wh0, hf.h8, r0);
        r1 = MFMA(wh1, hf.h8, r1);
        r2 = MFMA(wh2, hf.h8, r2);
        r3 = MFMA(wh3, hf.h8, r3);
        f32x2 gi, gf, gg, go;
        gi[0] = hi8 ? r0[2] : r0[0]; gi[1] = hi8 ? r0[3] : r0[1];
        gf[0] = hi8 ? r1[2] : r1[0]; gf[1] = hi8 ? r1[3] : r1[1];
        gg[0] = hi8 ? r2[2] : r2[0]; gg[1] = hi8 ? r2[3] : r2[1];
        go[0] = hi8 ? r3[2] : r3[0]; go[1] = hi8 ? r3[3] : r3[1];
        cell2p_(gi, gf, gg, go, cc, hv);
        hh = pkrne_(hv[0], hv[1]);
    };

    uint4 xb0 = xld(0), xb1 = xld(1), xb2 = xld(2), xb3 = xld(3);
    for (int s = 0; s < TT; s += 4) {
        step(xb0); xb0 = xld(s+4);
        step(xb1); xb1 = xld(s+5);
        step(xb2); xb2 = xld(s+6);
        step(xb3); xb3 = xld(s+7);
    }

    const int batch = tile*8 + c;
    float* hp = p.hT + ((size_t)(dir ? BB : 0) + batch)*16 + uu;
    float2 ho; ho.x = hv[0]; ho.y = hv[1];
    *(float2*)hp = ho;
}

// ---------------- phase C: MLP head ----------------
struct PC {
    const float* hT;
    const float *W1, *b1, *W2, *b2;
    float* out;
};

__global__ __launch_bounds__(64) void head_k(PC p) {
    const int B = blockIdx.x * 64 + threadIdx.x;
    const float* hf = p.hT + (size_t)B*16;
    const float* hb = p.hT + ((size_t)BB + B)*16;

    float z0[32];
#pragma unroll
    for (int k = 0; k < 16; ++k) z0[k] = elu_(hb[k]);       // feat = [hT_b, hT_f]
#pragma unroll
    for (int k = 0; k < 16; ++k) z0[16+k] = elu_(hf[k]);

    float z1[25];
#pragma unroll
    for (int o = 0; o < 25; ++o) {
        float a = p.b1[o];
#pragma unroll
        for (int k = 0; k < 32; ++k) a = fmaf(p.W1[o*32 + k], z0[k], a);
        z1[o] = elu_(a);
    }
#pragma unroll
    for (int o = 0; o < 20; ++o) {
        float a = p.b2[o];
#pragma unroll
        for (int k = 0; k < 25; ++k) a = fmaf(p.W2[o*25 + k], z1[k], a);
        p.out[(size_t)B*20 + o] = elu_(a);
    }
}

extern "C" void kernel_launch(void* const* d_in, const int* in_sizes, int n_in,
                              void* d_out, int out_size, void* d_ws, size_t ws_size,
                              hipStream_t stream) {
    (void)in_sizes; (void)n_in; (void)out_size;

    const size_t frag_bytes = (size_t)NT8 * TT * 512;                 // 128 MiB
    const size_t hT_bytes   = (size_t)2 * BB * 16 * sizeof(float);    // 512 KiB
    size_t hT_off = (ws_size >= frag_bytes + hT_bytes) ? frag_bytes
                                                       : (ws_size - hT_bytes);
    char* ws = (char*)d_ws;
    float* hT = (float*)(ws + hT_off);

    PA pa;
    pa.x = (const float*)d_in[0];
    pa.WihF = (const float*)d_in[1];  pa.WhhF = (const float*)d_in[2];
    pa.bihF = (const float*)d_in[3];  pa.bhhF = (const float*)d_in[4];
    pa.WihB = (const float*)d_in[5];  pa.WhhB = (const float*)d_in[6];
    pa.bihB = (const float*)d_in[7];  pa.bhhB = (const float*)d_in[8];
    pa.ws = ws;
    hipLaunchKernelGGL(phaseA_k, dim3(256), dim3(256), 0, stream, pa);

    PB pb;
    pb.WihF = (const float*)d_in[9];   pb.WhhF = (const float*)d_in[10];
    pb.bihF = (const float*)d_in[11];  pb.bhhF = (const float*)d_in[12];
    pb.WihB = (const float*)d_in[13];  pb.WhhB = (const float*)d_in[14];
    pb.bihB = (const float*)d_in[15];  pb.bhhB = (const float*)d_in[16];
    pb.ws = ws; pb.hT = hT;
    hipLaunchKernelGGL(phaseB_k, dim3(256), dim3(256), 0, stream, pb);

    PC pc;
    pc.hT = hT;
    pc.W1 = (const float*)d_in[17]; pc.b1 = (const float*)d_in[18];
    pc.W2 = (const float*)d_in[19]; pc.b2 = (const float*)d_in[20];
    pc.out = (float*)d_out;
    hipLaunchKernelGGL(head_k, dim3(BB/64), dim3(64), 0, stream, pc);
}

// Round 12
// 286.679 us; speedup vs baseline: 1.2606x; 1.0685x over previous
//
#include <hip/hip_runtime.h>
#include <stdint.h>

#define TT 512
#define BB 4096
#define NT8 512   // tiles of 8 batch columns
#define LOG2E 1.4426950408889634f

typedef _Float16 half8_t __attribute__((ext_vector_type(8)));
typedef __fp16 fp16x2_t __attribute__((ext_vector_type(2)));
typedef float f32x4 __attribute__((ext_vector_type(4)));
typedef float f32x2 __attribute__((ext_vector_type(2)));

union FragU { uint4 u4; half8_t h8; };
union PkU { fp16x2_t h2; unsigned int u; };

__device__ __forceinline__ float rcp_(float x){ return __builtin_amdgcn_rcpf(x); }
__device__ __forceinline__ float exp2_(float x){ return __builtin_amdgcn_exp2f(x); }
__device__ __forceinline__ float elu_(float x){ return x > 0.0f ? x : (exp2_(x * LOG2E) - 1.0f); }
__device__ __forceinline__ int mini_(int a, int b){ return a < b ? a : b; }
__device__ __forceinline__ float maskhi_(float x){ return __uint_as_float(__float_as_uint(x) & 0xFFFFE000u); }
__device__ __forceinline__ unsigned int pkrtz_(float a, float b){
    PkU p; p.h2 = __builtin_amdgcn_cvt_pkrtz(a, b); return p.u;
}
__device__ __forceinline__ unsigned int pkrne_(float a, float b){
    PkU p; p.h2[0] = (__fp16)a; p.h2[1] = (__fp16)b; return p.u;
}

__device__ __forceinline__ f32x4 MFMA(half8_t a, half8_t b, f32x4 c) {
    return __builtin_amdgcn_mfma_f32_16x16x32_f16(a, b, c, 0, 0, 0);
}

__device__ __forceinline__ f32x4 ld4_(const float* p){ return *(const f32x4*)p; }

// pack 8 f32 -> 8 f16 with scale (A-fragment slice; row = lane&15, k = 8*(lane>>4)+e)
__device__ __forceinline__ half8_t packA8s(const float* s, float sc) {
    half8_t h;
#pragma unroll
    for (int k = 0; k < 8; ++k) h[k] = (_Float16)(s[k] * sc);
    return h;
}
__device__ __forceinline__ half8_t zero8_() {
    half8_t h;
#pragma unroll
    for (int k = 0; k < 8; ++k) h[k] = (_Float16)0.0f;
    return h;
}

// Two-unit LSTM cell, f32x2-packed, shared-rcp sigmoids.
// Inputs PRESCALED: i,f,o rows by log2e; g rows by 2*log2e.
// 7 trans/unit (5 exp2 + 2 rcp). |g'|<~24 -> P<2^96, no overflow.
__device__ __forceinline__ void cell2p_(f32x2 gi, f32x2 gf, f32x2 gg, f32x2 go,
                                        f32x2& c, f32x2& h) {
    f32x2 ei, ef, eg, eo;
    ei[0] = exp2_(-gi[0]); ei[1] = exp2_(-gi[1]);
    ef[0] = exp2_(-gf[0]); ef[1] = exp2_(-gf[1]);
    eg[0] = exp2_(-gg[0]); eg[1] = exp2_(-gg[1]);
    eo[0] = exp2_(-go[0]); eo[1] = exp2_(-go[1]);
    const f32x2 one = {1.0f, 1.0f};
    f32x2 ai = one + ei, af = one + ef, ag = one + eg, ao = one + eo;
    f32x2 pif = ai * af, pgo = ag * ao;
    f32x2 P = pif * pgo;
    f32x2 R; R[0] = rcp_(P[0]); R[1] = rcp_(P[1]);
    f32x2 I = R * (af * pgo);
    f32x2 F = R * (ai * pgo);
    f32x2 Gt = R * (pif * ao);
    f32x2 O = R * (pif * ag);
    f32x2 G = Gt + Gt - one;            // tanh(g) = 2*sigmoid(2g)-1
    c = F * c + I * G;
    f32x2 ct = c * (-2.0f * LOG2E);
    f32x2 et; et[0] = exp2_(ct[0]); et[1] = exp2_(ct[1]);
    f32x2 den = one + et;
    f32x2 Rt; Rt[0] = rcp_(den[0]); Rt[1] = rcp_(den[1]);
    f32x2 T = Rt + Rt - one;
    h = O * T;
}

// Dup-8 scheme (8 real cols/chain, B col-slots 8-15 ≡ 0-7): lane (q,b),
// c=b&7, hi8=(b>=8) owns units uu=4q+2*hi8, uu+1 of col c, packed as one
// u32 hh (2x fp16 RNE). Recurrence is fp16-only: K rows 0-15 = h_hi,
// rows 16-31 matched by ZERO A-columns (so B content there is don't-care).

// ---------------- phase A: layer 0 (input dim 1), both directions ----------------
// (r11 verbatim — measured ~130 us: x folded into MFMA via A cols 16,17 = Wih,
//  B word0 of q=2 lanes = [x_hi,x_lo]; h-exchange via 4 shfl.)
struct PA {
    const float *x;
    const float *WihF, *WhhF, *bihF, *bhhF;
    const float *WihB, *WhhB, *bihB, *bhhB;
    char* ws;   // [tile8][t][512B]: col c at c*64: [f u0-15 hi | b u0-15 hi] fp16
};

__global__ __launch_bounds__(256) void phaseA_k(PA p) {
    const int tid = threadIdx.x;
    const int lane = tid & 63;
    const int wv   = tid >> 6;
    const int q = lane >> 4, b = lane & 15, c = b & 7;
    const bool hi8 = b >= 8;
    const int chain = blockIdx.x * 4 + wv;       // 1024 chains = 512 tiles x 2 dirs
    const int tile = chain >> 1, dir = chain & 1;

    const float* Wih = dir ? p.WihB : p.WihF;
    const float* Whh = dir ? p.WhhB : p.WhhF;
    const float* bih = dir ? p.bihB : p.bihF;
    const float* bhh = dir ? p.bhhB : p.bhhF;

    // A-frags: K=32 = [Whh(16) | Wih,Wih | zeros(14)]
    auto mkA = [&](int m, float sc)->half8_t {
        if (q < 2) return packA8s(Whh + (16*m + b)*16 + 8*q, sc);
        half8_t h = zero8_();
        if (q == 2) {
            float w = Wih[16*m + b] * sc;   // Wih0 is [64 x 1]
            h[0] = (_Float16)w;
            h[1] = (_Float16)w;
        }
        return h;
    };
    half8_t A0 = mkA(0, LOG2E);
    half8_t A1 = mkA(1, LOG2E);
    half8_t A2 = mkA(2, 2.0f*LOG2E);
    half8_t A3 = mkA(3, LOG2E);

    f32x4 bias0 = (ld4_(bih +      4*q) + ld4_(bhh +      4*q)) * LOG2E;
    f32x4 bias1 = (ld4_(bih + 16 + 4*q) + ld4_(bhh + 16 + 4*q)) * LOG2E;
    f32x4 bias2 = (ld4_(bih + 32 + 4*q) + ld4_(bhh + 32 + 4*q)) * (2.0f*LOG2E);
    f32x4 bias3 = (ld4_(bih + 48 + 4*q) + ld4_(bhh + 48 + 4*q)) * LOG2E;

    const int uu = 4*q + (hi8 ? 2 : 0);
    const int sa0 = 32*(q&1) + c;
    const int sa1 = sa0 + 8;
    const int sa2 = sa0 + 16;
    const int sa3 = sa0 + 24;
    const bool qlt2 = q < 2;
    const bool q2   = q == 2;

    unsigned int hh = 0u;           // this lane's packed unit pair (fp16 RNE)
    f32x2 cc = {0.f, 0.f};

    const char* xbase = (const char*)p.x + (size_t)tile*8*TT*4;   // uniform
    const int   xoff  = c*TT*4;                                   // invariant voffset
    char*       wsbase = p.ws + (size_t)tile*TT*512;              // uniform
    const int   woff  = c*64 + dir*32 + uu*2;

    auto xld = [&](int s_)->float {
        int s = mini_(s_, TT-1);
        int t = dir ? (TT-1-s) : s;
        return *(const float*)(xbase + (size_t)t*4 + xoff);
    };

    auto step = [&](float xv, int t) {
        float mh = maskhi_(xv);
        unsigned int xp = pkrtz_(mh, xv - mh);   // [x_hi, x_lo]
        unsigned int s0 = (unsigned int)__shfl((int)hh, sa0);
        unsigned int s1 = (unsigned int)__shfl((int)hh, sa1);
        unsigned int s2 = (unsigned int)__shfl((int)hh, sa2);
        unsigned int s3 = (unsigned int)__shfl((int)hh, sa3);
        FragU hf;
        hf.u4.x = qlt2 ? s0 : (q2 ? xp : 0u);
        hf.u4.y = qlt2 ? s1 : 0u;
        hf.u4.z = qlt2 ? s2 : 0u;
        hf.u4.w = qlt2 ? s3 : 0u;
        f32x4 r0 = MFMA(A0, hf.h8, bias0);
        f32x4 r1 = MFMA(A1, hf.h8, bias1);
        f32x4 r2 = MFMA(A2, hf.h8, bias2);
        f32x4 r3 = MFMA(A3, hf.h8, bias3);
        f32x2 gi, gf, gg, go;
        gi[0] = hi8 ? r0[2] : r0[0]; gi[1] = hi8 ? r0[3] : r0[1];
        gf[0] = hi8 ? r1[2] : r1[0]; gf[1] = hi8 ? r1[3] : r1[1];
        gg[0] = hi8 ? r2[2] : r2[0]; gg[1] = hi8 ? r2[3] : r2[1];
        go[0] = hi8 ? r3[2] : r3[0]; go[1] = hi8 ? r3[3] : r3[1];
        f32x2 hv;
        cell2p_(gi, gf, gg, go, cc, hv);
        hh = pkrne_(hv[0], hv[1]);
        *(unsigned int*)(wsbase + (size_t)t*512 + woff) = hh;
    };

    float xv0 = xld(0), xv1 = xld(1), xv2 = xld(2), xv3 = xld(3);
    for (int s = 0; s < TT; s += 4) {
        const int t0 = dir ? (TT-1-s) : s;
        const int d  = dir ? -1 : 1;
        step(xv0, t0      ); xv0 = xld(s+4);
        step(xv1, t0 + d  ); xv1 = xld(s+5);
        step(xv2, t0 + 2*d); xv2 = xld(s+6);
        step(xv3, t0 + 3*d); xv3 = xld(s+7);
    }
}

// ---------------- phase B: layer 1 (input dim 32 from ws), both directions ----------------
// LDS h-exchange (r9-proven, fp16-only): per wave 256B; col c at c*32 holds
// h_hi units 0-15 (2B each). Write: lane b32 hh at c*32+uu*2 (64 disjoint
// banks, conflict-free). Read: b128 at c*32+(q&1)*16 (4-way broadcast).
// q>=2 lanes read stale/garbage rows 16-31 — harmless (A cols 16-31 = 0).
// wi-MFMAs (input side) are precomputed ONE STEP AHEAD from prefetched ws
// so the recurrence chain is read -> 4 wh-MFMA -> cell only.
struct PB {
    const float *WihF, *WhhF, *bihF, *bhhF;
    const float *WihB, *WhhB, *bihB, *bhhB;
    const char* ws;
    float* hT;   // [dir][batch][16] f32
};

__global__ __launch_bounds__(256) void phaseB_k(PB p) {
    __shared__ uint4 ldsAll[4 * 16];   // 4 waves x 256 B
    const int tid = threadIdx.x;
    const int lane = tid & 63;
    const int wv   = tid >> 6;
    char* lds = (char*)ldsAll + wv * 256;
    const int q = lane >> 4, b = lane & 15, c = b & 7;
    const bool hi8 = b >= 8;
    const int chain = blockIdx.x * 4 + wv;
    const int tile = chain >> 1, dir = chain & 1;

    const float* Wih = dir ? p.WihB : p.WihF;
    const float* Whh = dir ? p.WhhB : p.WhhF;
    const float* bih = dir ? p.bihB : p.bihF;
    const float* bhh = dir ? p.bhhB : p.bhhF;

    const float SC0 = LOG2E, SC1 = LOG2E, SC2 = 2.0f*LOG2E, SC3 = LOG2E;

    half8_t wi0 = packA8s(Wih + (     b)*32 + 8*q, SC0);  // K=32 = [h0f;h0b]
    half8_t wi1 = packA8s(Wih + (16 + b)*32 + 8*q, SC1);
    half8_t wi2 = packA8s(Wih + (32 + b)*32 + 8*q, SC2);
    half8_t wi3 = packA8s(Wih + (48 + b)*32 + 8*q, SC3);

    // wh: K=32 = [Whh(16) | zeros(16)]
    half8_t wh0 = (q < 2) ? packA8s(Whh + (     b)*16 + 8*q, SC0) : zero8_();
    half8_t wh1 = (q < 2) ? packA8s(Whh + (16 + b)*16 + 8*q, SC1) : zero8_();
    half8_t wh2 = (q < 2) ? packA8s(Whh + (32 + b)*16 + 8*q, SC2) : zero8_();
    half8_t wh3 = (q < 2) ? packA8s(Whh + (48 + b)*16 + 8*q, SC3) : zero8_();

    f32x4 bias0 = (ld4_(bih +      4*q) + ld4_(bhh +      4*q)) * SC0;
    f32x4 bias1 = (ld4_(bih + 16 + 4*q) + ld4_(bhh + 16 + 4*q)) * SC1;
    f32x4 bias2 = (ld4_(bih + 32 + 4*q) + ld4_(bhh + 32 + 4*q)) * SC2;
    f32x4 bias3 = (ld4_(bih + 48 + 4*q) + ld4_(bhh + 48 + 4*q)) * SC3;

    const int uu  = 4*q + (hi8 ? 2 : 0);
    const int who = c*32 + uu*2;        // b32 write
    const int rdo = c*32 + (q&1)*16;    // b128 read

    ((unsigned int*)lds)[lane & 63] = 0u;   // zero 256 B (64 lanes x 4 B)
    __builtin_amdgcn_wave_barrier();

    f32x2 cc = {0.f, 0.f};
    f32x2 hv = {0.f, 0.f};

    const char* wsbase = p.ws + (size_t)tile*TT*512;   // uniform
    const int   xoff   = c*64 + q*16;                  // invariant voffset

    auto xld = [&](int s_)->uint4 {
        int s = mini_(s_, TT-1);
        int t = dir ? (TT-1-s) : s;
        return *(const uint4*)(wsbase + (size_t)t*512 + xoff);
    };

    auto wiM = [&](uint4 xin, f32x4& o0, f32x4& o1, f32x4& o2, f32x4& o3) {
        FragU xf; xf.u4 = xin;
        o0 = MFMA(wi0, xf.h8, bias0);
        o1 = MFMA(wi1, xf.h8, bias1);
        o2 = MFMA(wi2, xf.h8, bias2);
        o3 = MFMA(wi3, xf.h8, bias3);
    };

    auto stepWh = [&](f32x4 p0, f32x4 p1, f32x4 p2, f32x4 p3) {
        FragU hf; hf.u4 = *(const uint4*)(lds + rdo);
        f32x4 r0 = MFMA(wh0, hf.h8, p0);
        f32x4 r1 = MFMA(wh1, hf.h8, p1);
        f32x4 r2 = MFMA(wh2, hf.h8, p2);
        f32x4 r3 = MFMA(wh3, hf.h8, p3);
        f32x2 gi, gf, gg, go;
        gi[0] = hi8 ? r0[2] : r0[0]; gi[1] = hi8 ? r0[3] : r0[1];
        gf[0] = hi8 ? r1[2] : r1[0]; gf[1] = hi8 ? r1[3] : r1[1];
        gg[0] = hi8 ? r2[2] : r2[0]; gg[1] = hi8 ? r2[3] : r2[1];
        go[0] = hi8 ? r3[2] : r3[0]; go[1] = hi8 ? r3[3] : r3[1];
        cell2p_(gi, gf, gg, go, cc, hv);
        unsigned int hh = pkrne_(hv[0], hv[1]);
        *(unsigned int*)(lds + who) = hh;
        __builtin_amdgcn_wave_barrier();
    };

    uint4 xb0 = xld(0), xb1 = xld(1), xb2 = xld(2), xb3 = xld(3);
    f32x4 pa0, pa1, pa2, pa3, pb0, pb1, pb2, pb3;
    wiM(xb0, pa0, pa1, pa2, pa3);
    for (int s = 0; s < TT; s += 4) {
        wiM(xb1, pb0, pb1, pb2, pb3);      // step s+1's input side
        stepWh(pa0, pa1, pa2, pa3);        // step s
        xb0 = xld(s+4);
        wiM(xb2, pa0, pa1, pa2, pa3);      // step s+2
        stepWh(pb0, pb1, pb2, pb3);        // step s+1
        xb1 = xld(s+5);
        wiM(xb3, pb0, pb1, pb2, pb3);      // step s+3
        stepWh(pa0, pa1, pa2, pa3);        // step s+2
        xb2 = xld(s+6);
        wiM(xb0, pa0, pa1, pa2, pa3);      // step s+4 (xb0 already reloaded)
        stepWh(pb0, pb1, pb2, pb3);        // step s+3
        xb3 = xld(s+7);
    }

    const int batch = tile*8 + c;
    float* hp = p.hT + ((size_t)(dir ? BB : 0) + batch)*16 + uu;
    float2 ho; ho.x = hv[0]; ho.y = hv[1];
    *(float2*)hp = ho;
}

// ---------------- phase C: MLP head ----------------
struct PC {
    const float* hT;
    const float *W1, *b1, *W2, *b2;
    float* out;
};

__global__ __launch_bounds__(64) void head_k(PC p) {
    const int B = blockIdx.x * 64 + threadIdx.x;
    const float* hf = p.hT + (size_t)B*16;
    const float* hb = p.hT + ((size_t)BB + B)*16;

    float z0[32];
#pragma unroll
    for (int k = 0; k < 16; ++k) z0[k] = elu_(hb[k]);       // feat = [hT_b, hT_f]
#pragma unroll
    for (int k = 0; k < 16; ++k) z0[16+k] = elu_(hf[k]);

    float z1[25];
#pragma unroll
    for (int o = 0; o < 25; ++o) {
        float a = p.b1[o];
#pragma unroll
        for (int k = 0; k < 32; ++k) a = fmaf(p.W1[o*32 + k], z0[k], a);
        z1[o] = elu_(a);
    }
#pragma unroll
    for (int o = 0; o < 20; ++o) {
        float a = p.b2[o];
#pragma unroll
        for (int k = 0; k < 25; ++k) a = fmaf(p.W2[o*25 + k], z1[k], a);
        p.out[(size_t)B*20 + o] = elu_(a);
    }
}

extern "C" void kernel_launch(void* const* d_in, const int* in_sizes, int n_in,
                              void* d_out, int out_size, void* d_ws, size_t ws_size,
                              hipStream_t stream) {
    (void)in_sizes; (void)n_in; (void)out_size;

    const size_t frag_bytes = (size_t)NT8 * TT * 512;                 // 128 MiB
    const size_t hT_bytes   = (size_t)2 * BB * 16 * sizeof(float);    // 512 KiB
    size_t hT_off = (ws_size >= frag_bytes + hT_bytes) ? frag_bytes
                                                       : (ws_size - hT_bytes);
    char* ws = (char*)d_ws;
    float* hT = (float*)(ws + hT_off);

    PA pa;
    pa.x = (const float*)d_in[0];
    pa.WihF = (const float*)d_in[1];  pa.WhhF = (const float*)d_in[2];
    pa.bihF = (const float*)d_in[3];  pa.bhhF = (const float*)d_in[4];
    pa.WihB = (const float*)d_in[5];  pa.WhhB = (const float*)d_in[6];
    pa.bihB = (const float*)d_in[7];  pa.bhhB = (const float*)d_in[8];
    pa.ws = ws;
    hipLaunchKernelGGL(phaseA_k, dim3(256), dim3(256), 0, stream, pa);

    PB pb;
    pb.WihF = (const float*)d_in[9];   pb.WhhF = (const float*)d_in[10];
    pb.bihF = (const float*)d_in[11];  pb.bhhF = (const float*)d_in[12];
    pb.WihB = (const float*)d_in[13];  pb.WhhB = (const float*)d_in[14];
    pb.bihB = (const float*)d_in[15];  pb.bhhB = (const float*)d_in[16];
    pb.ws = ws; pb.hT = hT;
    hipLaunchKernelGGL(phaseB_k, dim3(256), dim3(256), 0, stream, pb);

    PC pc;
    pc.hT = hT;
    pc.W1 = (const float*)d_in[17]; pc.b1 = (const float*)d_in[18];
    pc.W2 = (const float*)d_in[19]; pc.b2 = (const float*)d_in[20];
    pc.out = (float*)d_out;
    hipLaunchKernelGGL(head_k, dim3(BB/64), dim3(64), 0, stream, pc);
}

// Round 13
// 279.437 us; speedup vs baseline: 1.2933x; 1.0259x over previous
//
#include <hip/hip_runtime.h>
#include <stdint.h>

#define TT 512
#define BB 4096
#define NT8 512   // tiles of 8 batch columns
#define LOG2E 1.4426950408889634f

typedef _Float16 half8_t __attribute__((ext_vector_type(8)));
typedef __fp16 fp16x2_t __attribute__((ext_vector_type(2)));
typedef float f32x4 __attribute__((ext_vector_type(4)));
typedef float f32x2 __attribute__((ext_vector_type(2)));

union FragU { uint4 u4; half8_t h8; };
union PkU { fp16x2_t h2; unsigned int u; };

__device__ __forceinline__ float rcp_(float x){ return __builtin_amdgcn_rcpf(x); }
__device__ __forceinline__ float exp2_(float x){ return __builtin_amdgcn_exp2f(x); }
__device__ __forceinline__ float elu_(float x){ return x > 0.0f ? x : (exp2_(x * LOG2E) - 1.0f); }
__device__ __forceinline__ int mini_(int a, int b){ return a < b ? a : b; }
__device__ __forceinline__ float maskhi_(float x){ return __uint_as_float(__float_as_uint(x) & 0xFFFFE000u); }
__device__ __forceinline__ unsigned int pkrtz_(float a, float b){
    PkU p; p.h2 = __builtin_amdgcn_cvt_pkrtz(a, b); return p.u;
}
__device__ __forceinline__ unsigned int pkrne_(float a, float b){
    PkU p; p.h2[0] = (__fp16)a; p.h2[1] = (__fp16)b; return p.u;
}

__device__ __forceinline__ f32x4 MFMA(half8_t a, half8_t b, f32x4 c) {
    return __builtin_amdgcn_mfma_f32_16x16x32_f16(a, b, c, 0, 0, 0);
}

__device__ __forceinline__ f32x4 ld4_(const float* p){ return *(const f32x4*)p; }

// pack 8 f32 -> 8 f16 with scale (A-fragment slice; row = lane&15, k = 8*(lane>>4)+e)
__device__ __forceinline__ half8_t packA8s(const float* s, float sc) {
    half8_t h;
#pragma unroll
    for (int k = 0; k < 8; ++k) h[k] = (_Float16)(s[k] * sc);
    return h;
}
__device__ __forceinline__ half8_t zero8_() {
    half8_t h;
#pragma unroll
    for (int k = 0; k < 8; ++k) h[k] = (_Float16)0.0f;
    return h;
}

// Two-unit LSTM cell, f32x2-packed, shared-rcp sigmoids.
// Inputs PRESCALED: i,f,o rows by log2e; g rows by 2*log2e.
// 7 trans/unit (5 exp2 + 2 rcp). |g'|<~24 -> P<2^96, no overflow.
__device__ __forceinline__ void cell2p_(f32x2 gi, f32x2 gf, f32x2 gg, f32x2 go,
                                        f32x2& c, f32x2& h) {
    f32x2 ei, ef, eg, eo;
    ei[0] = exp2_(-gi[0]); ei[1] = exp2_(-gi[1]);
    ef[0] = exp2_(-gf[0]); ef[1] = exp2_(-gf[1]);
    eg[0] = exp2_(-gg[0]); eg[1] = exp2_(-gg[1]);
    eo[0] = exp2_(-go[0]); eo[1] = exp2_(-go[1]);
    const f32x2 one = {1.0f, 1.0f};
    f32x2 ai = one + ei, af = one + ef, ag = one + eg, ao = one + eo;
    f32x2 pif = ai * af, pgo = ag * ao;
    f32x2 P = pif * pgo;
    f32x2 R; R[0] = rcp_(P[0]); R[1] = rcp_(P[1]);
    f32x2 I = R * (af * pgo);
    f32x2 F = R * (ai * pgo);
    f32x2 Gt = R * (pif * ao);
    f32x2 O = R * (pif * ag);
    f32x2 G = Gt + Gt - one;            // tanh(g) = 2*sigmoid(2g)-1
    c = F * c + I * G;
    f32x2 ct = c * (-2.0f * LOG2E);
    f32x2 et; et[0] = exp2_(ct[0]); et[1] = exp2_(ct[1]);
    f32x2 den = one + et;
    f32x2 Rt; Rt[0] = rcp_(den[0]); Rt[1] = rcp_(den[1]);
    f32x2 T = Rt + Rt - one;
    h = O * T;
}

// Dup-8 scheme (8 real cols/chain, B col-slots 8-15 ≡ 0-7): lane (q,b),
// c=b&7, hi8=(b>=8) owns units uu=4q+2*hi8, uu+1 of col c, packed as one
// u32 hh (2x fp16 RNE). Recurrence is fp16-only: K rows 0-15 = h_hi,
// rows 16-31 matched by ZERO A-columns (so B content there is don't-care).
//
// LDS h-exchange (proven in r12 phaseB): per wave 256B; col c at c*32 holds
// h_hi units 0-15 (2B each). Write: lane b32 hh at c*32+uu*2 (64 disjoint
// words, 2-way banks = free). Read: b128 at c*32+(q&1)*16 (4-way broadcast,
// conflict-free). q>=2 lanes read don't-care rows — their A columns are 0.

// ---------------- phase A: layer 0 (input dim 1), both directions ----------------
// x folded into the same MFMA: A cols 16,17 = Wih*SC (q=2 elems 0,1); after
// the LDS read, ONE cndmask injects [x_hi,x_lo] into word0 of q>=2 lanes
// (q=3 / words 1-3 hit zero A-columns -> harmless). Bias rides C (f32 exact).
struct PA {
    const float *x;
    const float *WihF, *WhhF, *bihF, *bhhF;
    const float *WihB, *WhhB, *bihB, *bhhB;
    char* ws;   // [tile8][t][512B]: col c at c*64: [f u0-15 hi | b u0-15 hi] fp16
};

__global__ __launch_bounds__(256) void phaseA_k(PA p) {
    __shared__ uint4 ldsAll[4 * 16];   // 4 waves x 256 B
    const int tid = threadIdx.x;
    const int lane = tid & 63;
    const int wv   = tid >> 6;
    char* lds = (char*)ldsAll + wv * 256;
    const int q = lane >> 4, b = lane & 15, c = b & 7;
    const bool hi8 = b >= 8;
    const int chain = blockIdx.x * 4 + wv;       // 1024 chains = 512 tiles x 2 dirs
    const int tile = chain >> 1, dir = chain & 1;

    const float* Wih = dir ? p.WihB : p.WihF;
    const float* Whh = dir ? p.WhhB : p.WhhF;
    const float* bih = dir ? p.bihB : p.bihF;
    const float* bhh = dir ? p.bhhB : p.bhhF;

    // A-frags: K=32 = [Whh(16) | Wih,Wih | zeros(14)]
    auto mkA = [&](int m, float sc)->half8_t {
        if (q < 2) return packA8s(Whh + (16*m + b)*16 + 8*q, sc);
        half8_t h = zero8_();
        if (q == 2) {
            float w = Wih[16*m + b] * sc;   // Wih0 is [64 x 1]
            h[0] = (_Float16)w;
            h[1] = (_Float16)w;
        }
        return h;
    };
    half8_t A0 = mkA(0, LOG2E);
    half8_t A1 = mkA(1, LOG2E);
    half8_t A2 = mkA(2, 2.0f*LOG2E);
    half8_t A3 = mkA(3, LOG2E);

    f32x4 bias0 = (ld4_(bih +      4*q) + ld4_(bhh +      4*q)) * LOG2E;
    f32x4 bias1 = (ld4_(bih + 16 + 4*q) + ld4_(bhh + 16 + 4*q)) * LOG2E;
    f32x4 bias2 = (ld4_(bih + 32 + 4*q) + ld4_(bhh + 32 + 4*q)) * (2.0f*LOG2E);
    f32x4 bias3 = (ld4_(bih + 48 + 4*q) + ld4_(bhh + 48 + 4*q)) * LOG2E;

    const int uu  = 4*q + (hi8 ? 2 : 0);
    const int who = c*32 + uu*2;        // b32 write
    const int rdo = c*32 + (q&1)*16;    // b128 read
    const bool qlt2 = q < 2;

    ((unsigned int*)lds)[lane & 63] = 0u;   // zero 256 B
    __builtin_amdgcn_wave_barrier();

    f32x2 cc = {0.f, 0.f};

    const char* xbase = (const char*)p.x + (size_t)tile*8*TT*4;   // uniform
    const int   xoff  = c*TT*4;                                   // invariant voffset
    char*       wsbase = p.ws + (size_t)tile*TT*512;              // uniform
    const int   woff  = c*64 + dir*32 + uu*2;

    auto xld = [&](int s_)->float {
        int s = mini_(s_, TT-1);
        int t = dir ? (TT-1-s) : s;
        return *(const float*)(xbase + (size_t)t*4 + xoff);
    };

    auto step = [&](float xv, int t) {
        float mh = maskhi_(xv);
        unsigned int xp = pkrtz_(mh, xv - mh);   // [x_hi, x_lo] (off-chain: xv prefetched)
        FragU hf; hf.u4 = *(const uint4*)(lds + rdo);
        hf.u4.x = qlt2 ? hf.u4.x : xp;           // single cndmask x-inject
        f32x4 r0 = MFMA(A0, hf.h8, bias0);
        f32x4 r1 = MFMA(A1, hf.h8, bias1);
        f32x4 r2 = MFMA(A2, hf.h8, bias2);
        f32x4 r3 = MFMA(A3, hf.h8, bias3);
        f32x2 gi, gf, gg, go;
        gi[0] = hi8 ? r0[2] : r0[0]; gi[1] = hi8 ? r0[3] : r0[1];
        gf[0] = hi8 ? r1[2] : r1[0]; gf[1] = hi8 ? r1[3] : r1[1];
        gg[0] = hi8 ? r2[2] : r2[0]; gg[1] = hi8 ? r2[3] : r2[1];
        go[0] = hi8 ? r3[2] : r3[0]; go[1] = hi8 ? r3[3] : r3[1];
        f32x2 hv;
        cell2p_(gi, gf, gg, go, cc, hv);
        unsigned int hh = pkrne_(hv[0], hv[1]);
        *(unsigned int*)(lds + who) = hh;
        *(unsigned int*)(wsbase + (size_t)t*512 + woff) = hh;
        __builtin_amdgcn_wave_barrier();
    };

    float xv0 = xld(0), xv1 = xld(1), xv2 = xld(2), xv3 = xld(3);
    for (int s = 0; s < TT; s += 4) {
        const int t0 = dir ? (TT-1-s) : s;
        const int d  = dir ? -1 : 1;
        step(xv0, t0      ); xv0 = xld(s+4);
        step(xv1, t0 + d  ); xv1 = xld(s+5);
        step(xv2, t0 + 2*d); xv2 = xld(s+6);
        step(xv3, t0 + 3*d); xv3 = xld(s+7);
    }
}

// ---------------- phase B: layer 1 (input dim 32 from ws), both directions ----------------
// (r12 verbatim — measured ~105 us.) wi-MFMAs precomputed one step ahead from
// prefetched ws; recurrence chain = read -> 4 wh-MFMA -> cell only.
struct PB {
    const float *WihF, *WhhF, *bihF, *bhhF;
    const float *WihB, *WhhB, *bihB, *bhhB;
    const char* ws;
    float* hT;   // [dir][batch][16] f32
};

__global__ __launch_bounds__(256) void phaseB_k(PB p) {
    __shared__ uint4 ldsAll[4 * 16];   // 4 waves x 256 B
    const int tid = threadIdx.x;
    const int lane = tid & 63;
    const int wv   = tid >> 6;
    char* lds = (char*)ldsAll + wv * 256;
    const int q = lane >> 4, b = lane & 15, c = b & 7;
    const bool hi8 = b >= 8;
    const int chain = blockIdx.x * 4 + wv;
    const int tile = chain >> 1, dir = chain & 1;

    const float* Wih = dir ? p.WihB : p.WihF;
    const float* Whh = dir ? p.WhhB : p.WhhF;
    const float* bih = dir ? p.bihB : p.bihF;
    const float* bhh = dir ? p.bhhB : p.bhhF;

    const float SC0 = LOG2E, SC1 = LOG2E, SC2 = 2.0f*LOG2E, SC3 = LOG2E;

    half8_t wi0 = packA8s(Wih + (     b)*32 + 8*q, SC0);  // K=32 = [h0f;h0b]
    half8_t wi1 = packA8s(Wih + (16 + b)*32 + 8*q, SC1);
    half8_t wi2 = packA8s(Wih + (32 + b)*32 + 8*q, SC2);
    half8_t wi3 = packA8s(Wih + (48 + b)*32 + 8*q, SC3);

    // wh: K=32 = [Whh(16) | zeros(16)]
    half8_t wh0 = (q < 2) ? packA8s(Whh + (     b)*16 + 8*q, SC0) : zero8_();
    half8_t wh1 = (q < 2) ? packA8s(Whh + (16 + b)*16 + 8*q, SC1) : zero8_();
    half8_t wh2 = (q < 2) ? packA8s(Whh + (32 + b)*16 + 8*q, SC2) : zero8_();
    half8_t wh3 = (q < 2) ? packA8s(Whh + (48 + b)*16 + 8*q, SC3) : zero8_();

    f32x4 bias0 = (ld4_(bih +      4*q) + ld4_(bhh +      4*q)) * SC0;
    f32x4 bias1 = (ld4_(bih + 16 + 4*q) + ld4_(bhh + 16 + 4*q)) * SC1;
    f32x4 bias2 = (ld4_(bih + 32 + 4*q) + ld4_(bhh + 32 + 4*q)) * SC2;
    f32x4 bias3 = (ld4_(bih + 48 + 4*q) + ld4_(bhh + 48 + 4*q)) * SC3;

    const int uu  = 4*q + (hi8 ? 2 : 0);
    const int who = c*32 + uu*2;        // b32 write
    const int rdo = c*32 + (q&1)*16;    // b128 read

    ((unsigned int*)lds)[lane & 63] = 0u;   // zero 256 B
    __builtin_amdgcn_wave_barrier();

    f32x2 cc = {0.f, 0.f};
    f32x2 hv = {0.f, 0.f};

    const char* wsbase = p.ws + (size_t)tile*TT*512;   // uniform
    const int   xoff   = c*64 + q*16;                  // invariant voffset

    auto xld = [&](int s_)->uint4 {
        int s = mini_(s_, TT-1);
        int t = dir ? (TT-1-s) : s;
        return *(const uint4*)(wsbase + (size_t)t*512 + xoff);
    };

    auto wiM = [&](uint4 xin, f32x4& o0, f32x4& o1, f32x4& o2, f32x4& o3) {
        FragU xf; xf.u4 = xin;
        o0 = MFMA(wi0, xf.h8, bias0);
        o1 = MFMA(wi1, xf.h8, bias1);
        o2 = MFMA(wi2, xf.h8, bias2);
        o3 = MFMA(wi3, xf.h8, bias3);
    };

    auto stepWh = [&](f32x4 p0, f32x4 p1, f32x4 p2, f32x4 p3) {
        FragU hf; hf.u4 = *(const uint4*)(lds + rdo);
        f32x4 r0 = MFMA(wh0, hf.h8, p0);
        f32x4 r1 = MFMA(wh1, hf.h8, p1);
        f32x4 r2 = MFMA(wh2, hf.h8, p2);
        f32x4 r3 = MFMA(wh3, hf.h8, p3);
        f32x2 gi, gf, gg, go;
        gi[0] = hi8 ? r0[2] : r0[0]; gi[1] = hi8 ? r0[3] : r0[1];
        gf[0] = hi8 ? r1[2] : r1[0]; gf[1] = hi8 ? r1[3] : r1[1];
        gg[0] = hi8 ? r2[2] : r2[0]; gg[1] = hi8 ? r2[3] : r2[1];
        go[0] = hi8 ? r3[2] : r3[0]; go[1] = hi8 ? r3[3] : r3[1];
        cell2p_(gi, gf, gg, go, cc, hv);
        unsigned int hh = pkrne_(hv[0], hv[1]);
        *(unsigned int*)(lds + who) = hh;
        __builtin_amdgcn_wave_barrier();
    };

    uint4 xb0 = xld(0), xb1 = xld(1), xb2 = xld(2), xb3 = xld(3);
    f32x4 pa0, pa1, pa2, pa3, pb0, pb1, pb2, pb3;
    wiM(xb0, pa0, pa1, pa2, pa3);
    for (int s = 0; s < TT; s += 4) {
        wiM(xb1, pb0, pb1, pb2, pb3);      // step s+1's input side
        stepWh(pa0, pa1, pa2, pa3);        // step s
        xb0 = xld(s+4);
        wiM(xb2, pa0, pa1, pa2, pa3);      // step s+2
        stepWh(pb0, pb1, pb2, pb3);        // step s+1
        xb1 = xld(s+5);
        wiM(xb3, pb0, pb1, pb2, pb3);      // step s+3
        stepWh(pa0, pa1, pa2, pa3);        // step s+2
        xb2 = xld(s+6);
        wiM(xb0, pa0, pa1, pa2, pa3);      // step s+4 (xb0 already reloaded)
        stepWh(pb0, pb1, pb2, pb3);        // step s+3
        xb3 = xld(s+7);
    }

    const int batch = tile*8 + c;
    float* hp = p.hT + ((size_t)(dir ? BB : 0) + batch)*16 + uu;
    float2 ho; ho.x = hv[0]; ho.y = hv[1];
    *(float2*)hp = ho;
}

// ---------------- phase C: MLP head ----------------
struct PC {
    const float* hT;
    const float *W1, *b1, *W2, *b2;
    float* out;
};

__global__ __launch_bounds__(64) void head_k(PC p) {
    const int B = blockIdx.x * 64 + threadIdx.x;
    const float* hf = p.hT + (size_t)B*16;
    const float* hb = p.hT + ((size_t)BB + B)*16;

    float z0[32];
#pragma unroll
    for (int k = 0; k < 16; ++k) z0[k] = elu_(hb[k]);       // feat = [hT_b, hT_f]
#pragma unroll
    for (int k = 0; k < 16; ++k) z0[16+k] = elu_(hf[k]);

    float z1[25];
#pragma unroll
    for (int o = 0; o < 25; ++o) {
        float a = p.b1[o];
#pragma unroll
        for (int k = 0; k < 32; ++k) a = fmaf(p.W1[o*32 + k], z0[k], a);
        z1[o] = elu_(a);
    }
#pragma unroll
    for (int o = 0; o < 20; ++o) {
        float a = p.b2[o];
#pragma unroll
        for (int k = 0; k < 25; ++k) a = fmaf(p.W2[o*25 + k], z1[k], a);
        p.out[(size_t)B*20 + o] = elu_(a);
    }
}

extern "C" void kernel_launch(void* const* d_in, const int* in_sizes, int n_in,
                              void* d_out, int out_size, void* d_ws, size_t ws_size,
                              hipStream_t stream) {
    (void)in_sizes; (void)n_in; (void)out_size;

    const size_t frag_bytes = (size_t)NT8 * TT * 512;                 // 128 MiB
    const size_t hT_bytes   = (size_t)2 * BB * 16 * sizeof(float);    // 512 KiB
    size_t hT_off = (ws_size >= frag_bytes + hT_bytes) ? frag_bytes
                                                       : (ws_size - hT_bytes);
    char* ws = (char*)d_ws;
    float* hT = (float*)(ws + hT_off);

    PA pa;
    pa.x = (const float*)d_in[0];
    pa.WihF = (const float*)d_in[1];  pa.WhhF = (const float*)d_in[2];
    pa.bihF = (const float*)d_in[3];  pa.bhhF = (const float*)d_in[4];
    pa.WihB = (const float*)d_in[5];  pa.WhhB = (const float*)d_in[6];
    pa.bihB = (const float*)d_in[7];  pa.bhhB = (const float*)d_in[8];
    pa.ws = ws;
    hipLaunchKernelGGL(phaseA_k, dim3(256), dim3(256), 0, stream, pa);

    PB pb;
    pb.WihF = (const float*)d_in[9];   pb.WhhF = (const float*)d_in[10];
    pb.bihF = (const float*)d_in[11];  pb.bhhF = (const float*)d_in[12];
    pb.WihB = (const float*)d_in[13];  pb.WhhB = (const float*)d_in[14];
    pb.bihB = (const float*)d_in[15];  pb.bhhB = (const float*)d_in[16];
    pb.ws = ws; pb.hT = hT;
    hipLaunchKernelGGL(phaseB_k, dim3(256), dim3(256), 0, stream, pb);

    PC pc;
    pc.hT = hT;
    pc.W1 = (const float*)d_in[17]; pc.b1 = (const float*)d_in[18];
    pc.W2 = (const float*)d_in[19]; pc.b2 = (const float*)d_in[20];
    pc.out = (float*)d_out;
    hipLaunchKernelGGL(head_k, dim3(BB/64), dim3(64), 0, stream, pc);
}